// Round 1
// baseline (958.578 us; speedup 1.0000x reference)
//
#include <hip/hip_runtime.h>

#define EPS_F 1e-5f

// ---------------------------------------------------------------------------
// Tiled fp32 GEMM:  C[b] = A(MxK, row-major) * B[b](KxN, row-major) + epilogue
// EPI 0: + bias(p0)                      (qkv)
// EPI 1: + bias(p0) + resid              (proj -> x1)
// EPI 2: BN(p0=g,p1=b,p2=m,p3=v) + SiLU  (mlp1)
// EPI 3: BN + resid                      (mlp2 -> out)
// Tile 128x128, BK=16, 256 threads, 8x8 per thread.
// ---------------------------------------------------------------------------
template<int EPI>
__global__ __launch_bounds__(256, 2)
void gemm_k(const float* __restrict__ A, const float* __restrict__ B,
            float* __restrict__ C,
            const float* __restrict__ p0, const float* __restrict__ p1,
            const float* __restrict__ p2, const float* __restrict__ p3,
            const float* __restrict__ resid,
            int M, int N, int K, size_t sB, size_t sC, size_t sR)
{
    __shared__ float As[16][132];   // stored transposed: As[k][m]
    __shared__ float Bs[16][132];   // Bs[k][n]

    const int b  = blockIdx.z;
    const float* Bb = B + (size_t)b * sB;
    float*       Cb = C + (size_t)b * sC;
    const float* Rb = (EPI == 1 || EPI == 3) ? (resid + (size_t)b * sR) : nullptr;

    const int n0 = blockIdx.x * 128;
    const int m0 = blockIdx.y * 128;
    const int t  = threadIdx.x;
    const int tx = t & 15;          // n-direction, 16 threads * 8 = 128
    const int ty = t >> 4;          // m-direction, 16 threads * 8 = 128

    // cooperative-load indices
    const int am = t >> 1;          // A row within tile (0..127)
    const int ak = (t & 1) * 8;     // A k-offset (0 or 8)
    const int bk = t >> 4;          // B k-row (0..15)
    const int bn = (t & 15) * 8;    // B col (0..120)

    float acc[8][8];
    #pragma unroll
    for (int i = 0; i < 8; ++i)
        #pragma unroll
        for (int j = 0; j < 8; ++j) acc[i][j] = 0.f;

    for (int k0 = 0; k0 < K; k0 += 16) {
        const float* Ap = A + (size_t)(m0 + am) * K + (k0 + ak);
        const float4 a0 = *(const float4*)Ap;
        const float4 a1 = *(const float4*)(Ap + 4);
        const float* Bp = Bb + (size_t)(k0 + bk) * N + (n0 + bn);
        const float4 b0 = *(const float4*)Bp;
        const float4 b1 = *(const float4*)(Bp + 4);

        As[ak + 0][am] = a0.x; As[ak + 1][am] = a0.y;
        As[ak + 2][am] = a0.z; As[ak + 3][am] = a0.w;
        As[ak + 4][am] = a1.x; As[ak + 5][am] = a1.y;
        As[ak + 6][am] = a1.z; As[ak + 7][am] = a1.w;
        *(float4*)&Bs[bk][bn]     = b0;
        *(float4*)&Bs[bk][bn + 4] = b1;
        __syncthreads();

        #pragma unroll
        for (int kk = 0; kk < 16; ++kk) {
            float a[8], bb[8];
            #pragma unroll
            for (int u = 0; u < 8; ++u) a[u]  = As[kk][ty * 8 + u];
            #pragma unroll
            for (int u = 0; u < 8; ++u) bb[u] = Bs[kk][tx * 8 + u];
            #pragma unroll
            for (int i = 0; i < 8; ++i)
                #pragma unroll
                for (int j = 0; j < 8; ++j)
                    acc[i][j] = fmaf(a[i], bb[j], acc[i][j]);
        }
        __syncthreads();
    }

    // epilogue
    #pragma unroll
    for (int i = 0; i < 8; ++i) {
        const int m = m0 + ty * 8 + i;
        float mul = 1.f, add = 0.f;
        if (EPI == 0 || EPI == 1) add = p0[m];
        if (EPI == 2 || EPI == 3) {
            const float inv = p0[m] * rsqrtf(p3[m] + EPS_F);
            mul = inv;
            add = p1[m] - p2[m] * inv;
        }
        const size_t row = (size_t)m * N + n0 + tx * 8;
        float o[8];
        #pragma unroll
        for (int j = 0; j < 8; ++j) {
            float z = acc[i][j] * mul + add;
            if (EPI == 2) z = z / (1.f + __expf(-z));           // SiLU
            if (EPI == 1 || EPI == 3) z += Rb[row + j];
            o[j] = z;
        }
        *(float4*)&Cb[row]     = make_float4(o[0], o[1], o[2], o[3]);
        *(float4*)&Cb[row + 4] = make_float4(o[4], o[5], o[6], o[7]);
    }
}

// ---------------------------------------------------------------------------
// Fused: 4-dilation 3x3-window attention + fc-mix + LayerNorm.
// qkv layout [B,768,HW]: o = qkvIdx*256 + dil*64 + c.
// Block = 256 thr = 4 waves; wave i handles dilation r=1<<i for 64 pixels.
// nh=1, hd=64 -> per-pixel softmax over 9 taps entirely in registers.
// Output y2 [B,256,HW] NCHW (channel = t*64+c) so proj is a plain GEMM.
// ---------------------------------------------------------------------------
__global__ __launch_bounds__(256, 2)
void attn_k(const float* __restrict__ qkv,
            const float* __restrict__ fc_w, const float* __restrict__ fc_b,
            const float* __restrict__ ln_g, const float* __restrict__ ln_b,
            float* __restrict__ y2)
{
    const int HW = 6400;
    __shared__ float st[4][64][64];   // [dil][c][px]  (64 KB)

    const int b   = blockIdx.y;
    const int hw0 = blockIdx.x * 64;
    const int t   = threadIdx.x;
    const int di  = t >> 6;           // dilation index == wave id
    const int px  = t & 63;
    const int hw  = hw0 + px;
    const int yy  = hw / 80;
    const int xx  = hw % 80;
    const int r   = 1 << di;          // DIL = (1,2,4,8)

    const float* qp = qkv + ((size_t)b * 768 +       di * 64) * HW + hw;
    const float* kp = qkv + ((size_t)b * 768 + 256 + di * 64) * HW;
    const float* vp = qkv + ((size_t)b * 768 + 512 + di * 64) * HW;

    int  off[9];
    bool ok[9];
    #pragma unroll
    for (int jy = 0; jy < 3; ++jy)
        #pragma unroll
        for (int jx = 0; jx < 3; ++jx) {
            const int ny = yy + (jy - 1) * r;
            const int nx = xx + (jx - 1) * r;
            const bool o = (ny >= 0) && (ny < 80) && (nx >= 0) && (nx < 80);
            ok[jy * 3 + jx]  = o;
            off[jy * 3 + jx] = o ? (ny * 80 + nx) : hw;  // safe addr when OOB
        }

    // ---- scores: s[j] = sum_c q[c] * k[c, j] ----
    float s[9];
    #pragma unroll
    for (int j = 0; j < 9; ++j) s[j] = 0.f;
    #pragma unroll 4
    for (int c = 0; c < 64; ++c) {
        const float qc = qp[(size_t)c * HW];
        const float* kc = kp + (size_t)c * HW;
        #pragma unroll
        for (int j = 0; j < 9; ++j) {
            const float kv = ok[j] ? kc[off[j]] : 0.f;   // zero-pad semantics
            s[j] = fmaf(qc, kv, s[j]);
        }
    }

    // ---- softmax over 9 taps (OOB taps participate with score 0) ----
    const float scale = 0.125f;      // hd^-0.5
    float mx = s[0] * scale;
    #pragma unroll
    for (int j = 1; j < 9; ++j) mx = fmaxf(mx, s[j] * scale);
    float e[9], sum = 0.f;
    #pragma unroll
    for (int j = 0; j < 9; ++j) { e[j] = __expf(s[j] * scale - mx); sum += e[j]; }
    const float isum = 1.f / sum;

    // ---- out[c] = sum_j w_j * v[c, j]  -> LDS ----
    #pragma unroll 4
    for (int c = 0; c < 64; ++c) {
        const float* vc = vp + (size_t)c * HW;
        float a = 0.f;
        #pragma unroll
        for (int j = 0; j < 9; ++j) {
            const float vv = ok[j] ? vc[off[j]] : 0.f;
            a = fmaf(e[j], vv, a);
        }
        st[di][c][px] = a * isum;
    }
    __syncthreads();

    // ---- fc-mix (4x4 across dilation slots) + residual + LayerNorm(64) ----
    float fw[4];
    #pragma unroll
    for (int s4 = 0; s4 < 4; ++s4) fw[s4] = fc_w[di * 4 + s4];
    const float fb = fc_b[di];

    float f[64];
    float mu = 0.f;
    #pragma unroll
    for (int c = 0; c < 64; ++c) {
        float v = fb + st[di][c][px];            // bias + residual
        #pragma unroll
        for (int s4 = 0; s4 < 4; ++s4) v = fmaf(fw[s4], st[s4][c][px], v);
        f[c] = v;
        mu += v;
    }
    mu *= (1.f / 64.f);
    float var = 0.f;
    #pragma unroll
    for (int c = 0; c < 64; ++c) { const float d = f[c] - mu; var = fmaf(d, d, var); }
    var *= (1.f / 64.f);
    const float rstd = rsqrtf(var + EPS_F);

    float* yo = y2 + ((size_t)b * 256 + di * 64) * HW + hw;
    #pragma unroll
    for (int c = 0; c < 64; ++c)
        yo[(size_t)c * HW] = (f[c] - mu) * rstd * ln_g[c] + ln_b[c];
}

// ---------------------------------------------------------------------------
extern "C" void kernel_launch(void* const* d_in, const int* in_sizes, int n_in,
                              void* d_out, int out_size, void* d_ws, size_t ws_size,
                              hipStream_t stream)
{
    const float* x      = (const float*)d_in[0];
    const float* qkv_w  = (const float*)d_in[1];
    const float* qkv_b  = (const float*)d_in[2];
    const float* fc_w   = (const float*)d_in[3];
    const float* fc_b   = (const float*)d_in[4];
    const float* ln_g   = (const float*)d_in[5];
    const float* ln_b   = (const float*)d_in[6];
    const float* proj_w = (const float*)d_in[7];
    const float* proj_b = (const float*)d_in[8];
    const float* w1     = (const float*)d_in[9];
    const float* bn1_g  = (const float*)d_in[10];
    const float* bn1_b  = (const float*)d_in[11];
    const float* bn1_m  = (const float*)d_in[12];
    const float* bn1_v  = (const float*)d_in[13];
    const float* w2     = (const float*)d_in[14];
    const float* bn2_g  = (const float*)d_in[15];
    const float* bn2_b  = (const float*)d_in[16];
    const float* bn2_m  = (const float*)d_in[17];
    const float* bn2_v  = (const float*)d_in[18];
    float* out = (float*)d_out;

    const int B = 8, HW = 6400;
    const size_t nQKV = (size_t)B * 768 * HW;   // 157.3 MB
    const size_t nCHW = (size_t)B * 256 * HW;   //  52.4 MB

    float* qkvb = (float*)d_ws;        // [B,768,HW]; later reused for h [B,512,HW]
    float* y2   = qkvb + nQKV;         // [B,256,HW]
    float* x1   = y2 + nCHW;           // [B,256,HW]
    float* h    = qkvb;                // alias: qkv dead after attn_k

    dim3 blk(256);

    // 1) qkv = qkv_w * x + qkv_b        M=768 K=256
    gemm_k<0><<<dim3(50, 6, B), blk, 0, stream>>>(
        qkv_w, x, qkvb, qkv_b, nullptr, nullptr, nullptr, nullptr,
        768, HW, 256, (size_t)256 * HW, (size_t)768 * HW, 0);

    // 2) attention + fc-mix + LN -> y2 (NCHW)
    attn_k<<<dim3(100, B), blk, 0, stream>>>(qkvb, fc_w, fc_b, ln_g, ln_b, y2);

    // 3) x1 = proj_w * y2 + proj_b + x  M=256 K=256
    gemm_k<1><<<dim3(50, 2, B), blk, 0, stream>>>(
        proj_w, y2, x1, proj_b, nullptr, nullptr, nullptr, x,
        256, HW, 256, (size_t)256 * HW, (size_t)256 * HW, (size_t)256 * HW);

    // 4) h = silu(bn1(w1 * x1))         M=512 K=256
    gemm_k<2><<<dim3(50, 4, B), blk, 0, stream>>>(
        w1, x1, h, bn1_g, bn1_b, bn1_m, bn1_v, nullptr,
        512, HW, 256, (size_t)256 * HW, (size_t)512 * HW, 0);

    // 5) out = bn2(w2 * h) + x1         M=256 K=512
    gemm_k<3><<<dim3(50, 2, B), blk, 0, stream>>>(
        w2, h, out, bn2_g, bn2_b, bn2_m, bn2_v, x1,
        256, HW, 512, (size_t)512 * HW, (size_t)256 * HW, (size_t)256 * HW);
}

// Round 2
// 458.215 us; speedup vs baseline: 2.0920x; 2.0920x over previous
//
#include <hip/hip_runtime.h>

#define EPS_F 1e-5f

typedef __attribute__((ext_vector_type(8))) short short8;
typedef __attribute__((ext_vector_type(4))) float f32x4;
typedef __attribute__((ext_vector_type(4))) unsigned short ushort4v;
typedef __attribute__((address_space(1))) void gvoid;
typedef __attribute__((address_space(3))) void svoid;

__device__ __forceinline__ float bf2f(unsigned short u){
    union { unsigned int i; float f; } v; v.i = ((unsigned int)u) << 16; return v.f;
}
__device__ __forceinline__ unsigned short f2bf(float f){
    union { float f; unsigned int i; } v; v.f = f;
    unsigned int r = v.i + 0x7FFFu + ((v.i >> 16) & 1u);
    return (unsigned short)(r >> 16);
}

// ---------------------------------------------------------------------------
// bf16 MFMA GEMM: C[m][n] = sum_k A[m][k] * Act[n][k]   (both K-contig)
//   A  : bf16 [M][K] row-major (weights)
//   Bt : bf16 [B][N][K] (activations NHWC)
// EPI 0: +bias              -> outT NHWC bf16            (qkv)
// EPI 1: +bias +resid(NCHW) -> outT NHWC bf16 + outF f32 (proj -> x1)
// EPI 2: BN+SiLU            -> outT NHWC bf16            (mlp1)
// EPI 3: BN+resid(NCHW)     -> outF f32 NCHW             (mlp2 -> out)
// 128x128 tile, BK=64, 4 waves (2x2), wave tile 64x64 = 4x4 MFMA frags.
// LDS XOR-swizzle: chunk ^= (row&7); applied on pre-swizzled global src
// (global_load_lds writes linearly) and on the ds_read side (involution).
// ---------------------------------------------------------------------------
template<int EPI>
__global__ __launch_bounds__(256, 2)
void mm_k(const short* __restrict__ A, const short* __restrict__ Bt,
          const int M, const int K,
          const float* __restrict__ p0, const float* __restrict__ p1,
          const float* __restrict__ p2, const float* __restrict__ p3,
          const float* __restrict__ resid,
          short* __restrict__ outT, float* __restrict__ outF)
{
    const int N = 6400;
    __shared__ short lsA[128 * 64];
    __shared__ short lsB[128 * 64];

    const int b  = blockIdx.z;
    const int n0 = blockIdx.x * 128;
    const int m0 = blockIdx.y * 128;
    const int t  = threadIdx.x;
    const int l  = t & 63;
    const int w  = t >> 6;
    const int wr = w >> 1, wc = w & 1;

    const short* Bb = Bt + (size_t)b * N * K;

    f32x4 acc[4][4];
    #pragma unroll
    for (int i = 0; i < 4; ++i)
        #pragma unroll
        for (int j = 0; j < 4; ++j) acc[i][j] = (f32x4){0.f, 0.f, 0.f, 0.f};

    const int rsub = l >> 3;   // 0..7: row within 8-row stage group
    const int csub = l & 7;    // 0..7: 16B chunk within 128B row

    for (int k0 = 0; k0 < K; k0 += 64) {
        #pragma unroll
        for (int q = 0; q < 4; ++q) {
            const int row = (w * 4 + q) * 8 + rsub;      // tile row 0..127
            const int cs  = csub ^ (row & 7);            // pre-swizzled src chunk
            const short* ga = A  + (size_t)(m0 + row) * K + k0 + (cs << 3);
            __builtin_amdgcn_global_load_lds((gvoid*)ga, (svoid*)(lsA + (w * 4 + q) * 512), 16, 0, 0);
            const short* gb = Bb + (size_t)(n0 + row) * K + k0 + (cs << 3);
            __builtin_amdgcn_global_load_lds((gvoid*)gb, (svoid*)(lsB + (w * 4 + q) * 512), 16, 0, 0);
        }
        __syncthreads();

        #pragma unroll
        for (int ks = 0; ks < 2; ++ks) {
            short8 av[4], bv[4];
            const int cfr = ks * 4 + (l >> 4);           // wanted k-chunk 0..7
            #pragma unroll
            for (int mi = 0; mi < 4; ++mi) {
                const int row = wr * 64 + mi * 16 + (l & 15);
                av[mi] = *(const short8*)&lsA[row * 64 + ((cfr ^ (row & 7)) << 3)];
            }
            #pragma unroll
            for (int ni = 0; ni < 4; ++ni) {
                const int row = wc * 64 + ni * 16 + (l & 15);
                bv[ni] = *(const short8*)&lsB[row * 64 + ((cfr ^ (row & 7)) << 3)];
            }
            #pragma unroll
            for (int mi = 0; mi < 4; ++mi)
                #pragma unroll
                for (int ni = 0; ni < 4; ++ni)
                    acc[mi][ni] = __builtin_amdgcn_mfma_f32_16x16x32_bf16(
                        av[mi], bv[ni], acc[mi][ni], 0, 0, 0);
        }
        __syncthreads();
    }

    // epilogue: C/D layout col = l&15, row = (l>>4)*4 + j  [m89-verified]
    const int mq = (l >> 4) * 4;
    const int nq = l & 15;
    #pragma unroll
    for (int mi = 0; mi < 4; ++mi) {
        const int mb = m0 + wr * 64 + mi * 16 + mq;
        float mul[4], add[4];
        #pragma unroll
        for (int j = 0; j < 4; ++j) {
            const int m = mb + j;
            if (EPI == 0 || EPI == 1) { mul[j] = 1.f; add[j] = p0[m]; }
            else { const float inv = p0[m] * rsqrtf(p3[m] + EPS_F);
                   mul[j] = inv; add[j] = p1[m] - p2[m] * inv; }
        }
        #pragma unroll
        for (int ni = 0; ni < 4; ++ni) {
            const int n = n0 + wc * 64 + ni * 16 + nq;
            float z[4];
            #pragma unroll
            for (int j = 0; j < 4; ++j) {
                z[j] = acc[mi][ni][j] * mul[j] + add[j];
                if (EPI == 2) z[j] = z[j] / (1.f + __expf(-z[j]));       // SiLU
                if (EPI == 1 || EPI == 3)
                    z[j] += resid[((size_t)b * M + mb + j) * N + n];
            }
            if (EPI == 0 || EPI == 1 || EPI == 2) {
                ushort4v u;
                #pragma unroll
                for (int j = 0; j < 4; ++j) u[j] = f2bf(z[j]);
                *(ushort4v*)&outT[((size_t)b * N + n) * M + mb] = u;     // NHWC, 8B/lane
            }
            if (EPI == 1 || EPI == 3) {
                #pragma unroll
                for (int j = 0; j < 4; ++j)
                    outF[((size_t)b * M + mb + j) * N + n] = z[j];       // NCHW f32
            }
        }
    }
}

// ---------------------------------------------------------------------------
// Attention on NHWC bf16 qkv [B][6400][768] (chan = qsel*256 + di*64 + c).
// Block = 4 waves; wave di handles dilation 1<<di for 64 pixels.
// Vectorized short8 loads; softmax over 9 taps in registers; fc-mix + LN
// through LDS; writes y2 NHWC bf16 [B][6400][256].
// ---------------------------------------------------------------------------
__global__ __launch_bounds__(256, 2)
void attn_k(const short* __restrict__ qkvt,
            const float* __restrict__ fc_w, const float* __restrict__ fc_b,
            const float* __restrict__ ln_g, const float* __restrict__ ln_b,
            short* __restrict__ y2t)
{
    __shared__ float st[4][64][64];

    const int b   = blockIdx.y;
    const int hw0 = blockIdx.x * 64;
    const int t   = threadIdx.x;
    const int di  = t >> 6;
    const int px  = t & 63;
    const int hw  = hw0 + px;
    const int yy  = hw / 80;
    const int xx  = hw % 80;
    const int r   = 1 << di;

    int  off[9];
    bool ok[9];
    #pragma unroll
    for (int jy = 0; jy < 3; ++jy)
        #pragma unroll
        for (int jx = 0; jx < 3; ++jx) {
            const int ny = yy + (jy - 1) * r;
            const int nx = xx + (jx - 1) * r;
            const bool o = (ny >= 0) && (ny < 80) && (nx >= 0) && (nx < 80);
            ok[jy * 3 + jx]  = o;
            off[jy * 3 + jx] = o ? (ny * 80 + nx) : 0;
        }

    // q -> registers (fp32)
    const short* qp = qkvt + ((size_t)b * 6400 + hw) * 768 + di * 64;
    float qf[64];
    #pragma unroll
    for (int c8 = 0; c8 < 8; ++c8) {
        const short8 v = *(const short8*)&qp[c8 * 8];
        #pragma unroll
        for (int u = 0; u < 8; ++u) qf[c8 * 8 + u] = bf2f((unsigned short)v[u]);
    }

    // scores
    float s[9];
    #pragma unroll
    for (int j = 0; j < 9; ++j) s[j] = 0.f;
    #pragma unroll
    for (int j = 0; j < 9; ++j) if (ok[j]) {
        const short* kp = qkvt + ((size_t)b * 6400 + off[j]) * 768 + 256 + di * 64;
        float a = 0.f;
        #pragma unroll
        for (int c8 = 0; c8 < 8; ++c8) {
            const short8 kv = *(const short8*)&kp[c8 * 8];
            #pragma unroll
            for (int u = 0; u < 8; ++u)
                a = fmaf(qf[c8 * 8 + u], bf2f((unsigned short)kv[u]), a);
        }
        s[j] = a;
    }

    // softmax (OOB taps participate with logit 0, matching zero-pad semantics)
    const float scale = 0.125f;
    float mx = s[0] * scale;
    #pragma unroll
    for (int j = 1; j < 9; ++j) mx = fmaxf(mx, s[j] * scale);
    float e[9], sum = 0.f;
    #pragma unroll
    for (int j = 0; j < 9; ++j) { e[j] = __expf(s[j] * scale - mx); sum += e[j]; }
    const float isum = 1.f / sum;

    // PV, streamed per 8-channel chunk
    #pragma unroll
    for (int c8 = 0; c8 < 8; ++c8) {
        float o[8];
        #pragma unroll
        for (int u = 0; u < 8; ++u) o[u] = 0.f;
        #pragma unroll
        for (int j = 0; j < 9; ++j) if (ok[j]) {
            const short* vp = qkvt + ((size_t)b * 6400 + off[j]) * 768 + 512 + di * 64;
            const short8 vv = *(const short8*)&vp[c8 * 8];
            #pragma unroll
            for (int u = 0; u < 8; ++u)
                o[u] = fmaf(e[j], bf2f((unsigned short)vv[u]), o[u]);
        }
        #pragma unroll
        for (int u = 0; u < 8; ++u) st[di][c8 * 8 + u][px] = o[u] * isum;
    }
    __syncthreads();

    // fc-mix + residual + LayerNorm(64)
    float fwv[4];
    #pragma unroll
    for (int s4 = 0; s4 < 4; ++s4) fwv[s4] = fc_w[di * 4 + s4];
    const float fb = fc_b[di];

    float f[64], mu = 0.f;
    #pragma unroll
    for (int c = 0; c < 64; ++c) {
        float v = fb + st[di][c][px];
        #pragma unroll
        for (int s4 = 0; s4 < 4; ++s4) v = fmaf(fwv[s4], st[s4][c][px], v);
        f[c] = v; mu += v;
    }
    mu *= (1.f / 64.f);
    float var = 0.f;
    #pragma unroll
    for (int c = 0; c < 64; ++c) { const float d = f[c] - mu; var = fmaf(d, d, var); }
    var *= (1.f / 64.f);
    const float rstd = rsqrtf(var + EPS_F);

    short* yo = y2t + ((size_t)b * 6400 + hw) * 256 + di * 64;
    #pragma unroll
    for (int c8 = 0; c8 < 8; ++c8) {
        short8 v;
        #pragma unroll
        for (int u = 0; u < 8; ++u) {
            const int c = c8 * 8 + u;
            v[u] = (short)f2bf((f[c] - mu) * rstd * ln_g[c] + ln_b[c]);
        }
        *(short8*)&yo[c8 * 8] = v;
    }
}

// ---------------------------------------------------------------------------
// x NCHW f32 -> xt NHWC bf16
// ---------------------------------------------------------------------------
__global__ void xt_k(const float* __restrict__ x, short* __restrict__ xt)
{
    const int b  = blockIdx.y;
    const int hw = blockIdx.x * 256 + threadIdx.x;
    const float* xb = x + (size_t)b * 256 * 6400 + hw;
    short* o = xt + ((size_t)b * 6400 + hw) * 256;
    #pragma unroll 4
    for (int c8 = 0; c8 < 32; ++c8) {
        short8 v;
        #pragma unroll
        for (int u = 0; u < 8; ++u)
            v[u] = (short)f2bf(xb[(size_t)(c8 * 8 + u) * 6400]);
        *(short8*)&o[c8 * 8] = v;
    }
}

// ---------------------------------------------------------------------------
// fp32 -> bf16 weight conversion (qkv_w | proj_w | w1 | w2 concatenated)
// ---------------------------------------------------------------------------
__global__ void wc_k(const float* __restrict__ a, const float* __restrict__ bb,
                     const float* __restrict__ c, const float* __restrict__ d,
                     short* __restrict__ o)
{
    const int i = blockIdx.x * 256 + threadIdx.x;   // 0 .. 524287
    float v;
    if      (i < 196608)  v = a[i];
    else if (i < 262144)  v = bb[i - 196608];
    else if (i < 393216)  v = c[i - 262144];
    else                  v = d[i - 393216];
    o[i] = (short)f2bf(v);
}

// ---------------------------------------------------------------------------
extern "C" void kernel_launch(void* const* d_in, const int* in_sizes, int n_in,
                              void* d_out, int out_size, void* d_ws, size_t ws_size,
                              hipStream_t stream)
{
    const float* x      = (const float*)d_in[0];
    const float* qkv_w  = (const float*)d_in[1];
    const float* qkv_b  = (const float*)d_in[2];
    const float* fc_w   = (const float*)d_in[3];
    const float* fc_b   = (const float*)d_in[4];
    const float* ln_g   = (const float*)d_in[5];
    const float* ln_b   = (const float*)d_in[6];
    const float* proj_w = (const float*)d_in[7];
    const float* proj_b = (const float*)d_in[8];
    const float* w1     = (const float*)d_in[9];
    const float* bn1_g  = (const float*)d_in[10];
    const float* bn1_b  = (const float*)d_in[11];
    const float* bn1_m  = (const float*)d_in[12];
    const float* bn1_v  = (const float*)d_in[13];
    const float* w2     = (const float*)d_in[14];
    const float* bn2_g  = (const float*)d_in[15];
    const float* bn2_b  = (const float*)d_in[16];
    const float* bn2_m  = (const float*)d_in[17];
    const float* bn2_v  = (const float*)d_in[18];
    float* out = (float*)d_out;

    const int B = 8, HW = 6400;

    // workspace layout (bytes)
    char* ws = (char*)d_ws;
    short* wqkvb = (short*)(ws + 0);                    // 196608 bf16
    short* wprojb = wqkvb + 196608;                     //  65536
    short* w1b    = wprojb + 65536;                     // 131072
    short* w2b    = w1b + 131072;                       // 131072
    short* xt     = (short*)(ws + 1048576);             // [B][HW][256]
    short* qkvt   = (short*)(ws + 27262976);            // [B][HW][768]; later h [B][HW][512]
    short* y2t    = (short*)(ws + 105906176);           // [B][HW][256]
    short* x1t    = (short*)(ws + 132120576);           // [B][HW][256]
    float* x1f    = (float*)(ws + 158334976);           // [B][256][HW] f32
    short* h      = qkvt;

    dim3 blk(256);

    // 0) weights -> bf16
    wc_k<<<dim3(2048), blk, 0, stream>>>(qkv_w, proj_w, w1, w2, wqkvb);

    // 1) x -> NHWC bf16
    xt_k<<<dim3(25, B), blk, 0, stream>>>(x, xt);

    // 2) qkv GEMM: M=768 K=256 -> qkvt NHWC (+bias)
    mm_k<0><<<dim3(50, 6, B), blk, 0, stream>>>(
        wqkvb, xt, 768, 256, qkv_b, nullptr, nullptr, nullptr, nullptr,
        qkvt, nullptr);

    // 3) attention + fc-mix + LN -> y2t NHWC
    attn_k<<<dim3(100, B), blk, 0, stream>>>(qkvt, fc_w, fc_b, ln_g, ln_b, y2t);

    // 4) proj GEMM: M=256 K=256, +bias +x -> x1t (bf16 NHWC) and x1f (f32 NCHW)
    mm_k<1><<<dim3(50, 2, B), blk, 0, stream>>>(
        wprojb, y2t, 256, 256, proj_b, nullptr, nullptr, nullptr, x,
        x1t, x1f);

    // 5) mlp1: M=512 K=256, BN1+SiLU -> h NHWC bf16
    mm_k<2><<<dim3(50, 4, B), blk, 0, stream>>>(
        w1b, x1t, 512, 256, bn1_g, bn1_b, bn1_m, bn1_v, nullptr,
        h, nullptr);

    // 6) mlp2: M=256 K=512, BN2 + x1 resid -> out f32 NCHW
    mm_k<3><<<dim3(50, 2, B), blk, 0, stream>>>(
        w2b, h, 256, 512, bn2_g, bn2_b, bn2_m, bn2_v, x1f,
        nullptr, out);
}

// Round 5
// 439.785 us; speedup vs baseline: 2.1797x; 1.0419x over previous
//
#include <hip/hip_runtime.h>

#define EPS_F 1e-5f

typedef __attribute__((ext_vector_type(8))) short short8;
typedef __attribute__((ext_vector_type(4))) float f32x4;
typedef __attribute__((ext_vector_type(4))) unsigned short ushort4v;
typedef __attribute__((address_space(1))) void gvoid;
typedef __attribute__((address_space(3))) void svoid;

__device__ __forceinline__ float bf2f(unsigned short u){
    union { unsigned int i; float f; } v; v.i = ((unsigned int)u) << 16; return v.f;
}
__device__ __forceinline__ unsigned short f2bf(float f){
    union { float f; unsigned int i; } v; v.f = f;
    unsigned int r = v.i + 0x7FFFu + ((v.i >> 16) & 1u);
    return (unsigned short)(r >> 16);
}

// ---------------------------------------------------------------------------
// bf16 MFMA GEMM: C[m][n] = sum_k A[m][k] * Act[n][k]   (both K-contig)
// Flat grid with XCD swizzle: id&7 = batch (-> XCD), id>>3 = n-tile + 50*m-tile.
// EPI 0: +bias              -> outT NHWC bf16            (qkv)
// EPI 1: +bias +resid(NCHW) -> outT NHWC bf16 + outF f32 (proj -> x1)
// EPI 2: BN+SiLU            -> outT NHWC bf16            (mlp1)
// EPI 3: BN+resid(NCHW)     -> outF f32 NCHW             (mlp2 -> out)
// ---------------------------------------------------------------------------
template<int EPI>
__global__ __launch_bounds__(256, 2)
void mm_k(const short* __restrict__ A, const short* __restrict__ Bt,
          const int M, const int K,
          const float* __restrict__ p0, const float* __restrict__ p1,
          const float* __restrict__ p2, const float* __restrict__ p3,
          const float* __restrict__ resid,
          short* __restrict__ outT, float* __restrict__ outF)
{
    const int N = 6400;
    __shared__ short lsA[128 * 64];
    __shared__ short lsB[128 * 64];

    const int id = blockIdx.x;
    const int b  = id & 7;
    const int rr = id >> 3;
    const int n0 = (rr % 50) * 128;
    const int m0 = (rr / 50) * 128;
    const int t  = threadIdx.x;
    const int l  = t & 63;
    const int w  = t >> 6;
    const int wr = w >> 1, wc = w & 1;

    const short* Bb = Bt + (size_t)b * N * K;

    f32x4 acc[4][4];
    #pragma unroll
    for (int i = 0; i < 4; ++i)
        #pragma unroll
        for (int j = 0; j < 4; ++j) acc[i][j] = (f32x4){0.f, 0.f, 0.f, 0.f};

    const int rsub = l >> 3;   // 0..7: row within 8-row stage group
    const int csub = l & 7;    // 0..7: 16B chunk within 128B row

    for (int k0 = 0; k0 < K; k0 += 64) {
        #pragma unroll
        for (int q = 0; q < 4; ++q) {
            const int row = (w * 4 + q) * 8 + rsub;      // tile row 0..127
            const int cs  = csub ^ (row & 7);            // pre-swizzled src chunk
            const short* ga = A  + (size_t)(m0 + row) * K + k0 + (cs << 3);
            __builtin_amdgcn_global_load_lds((gvoid*)ga, (svoid*)(lsA + (w * 4 + q) * 512), 16, 0, 0);
            const short* gb = Bb + (size_t)(n0 + row) * K + k0 + (cs << 3);
            __builtin_amdgcn_global_load_lds((gvoid*)gb, (svoid*)(lsB + (w * 4 + q) * 512), 16, 0, 0);
        }
        __syncthreads();

        #pragma unroll
        for (int ks = 0; ks < 2; ++ks) {
            short8 av[4], bv[4];
            const int cfr = ks * 4 + (l >> 4);           // wanted k-chunk 0..7
            #pragma unroll
            for (int mi = 0; mi < 4; ++mi) {
                const int row = wr * 64 + mi * 16 + (l & 15);
                av[mi] = *(const short8*)&lsA[row * 64 + ((cfr ^ (row & 7)) << 3)];
            }
            #pragma unroll
            for (int ni = 0; ni < 4; ++ni) {
                const int row = wc * 64 + ni * 16 + (l & 15);
                bv[ni] = *(const short8*)&lsB[row * 64 + ((cfr ^ (row & 7)) << 3)];
            }
            #pragma unroll
            for (int mi = 0; mi < 4; ++mi)
                #pragma unroll
                for (int ni = 0; ni < 4; ++ni)
                    acc[mi][ni] = __builtin_amdgcn_mfma_f32_16x16x32_bf16(
                        av[mi], bv[ni], acc[mi][ni], 0, 0, 0);
        }
        __syncthreads();
    }

    // epilogue: C/D layout col = l&15, row = (l>>4)*4 + j  [m89-verified]
    const int mq = (l >> 4) * 4;
    const int nq = l & 15;
    #pragma unroll
    for (int mi = 0; mi < 4; ++mi) {
        const int mb = m0 + wr * 64 + mi * 16 + mq;
        float mul[4], add[4];
        #pragma unroll
        for (int j = 0; j < 4; ++j) {
            const int m = mb + j;
            if (EPI == 0 || EPI == 1) { mul[j] = 1.f; add[j] = p0[m]; }
            else { const float inv = p0[m] * rsqrtf(p3[m] + EPS_F);
                   mul[j] = inv; add[j] = p1[m] - p2[m] * inv; }
        }
        #pragma unroll
        for (int ni = 0; ni < 4; ++ni) {
            const int n = n0 + wc * 64 + ni * 16 + nq;
            float z[4];
            #pragma unroll
            for (int j = 0; j < 4; ++j) {
                z[j] = acc[mi][ni][j] * mul[j] + add[j];
                if (EPI == 2) z[j] = z[j] / (1.f + __expf(-z[j]));       // SiLU
                if (EPI == 1 || EPI == 3)
                    z[j] += resid[((size_t)b * M + mb + j) * N + n];
            }
            if (EPI == 0 || EPI == 1 || EPI == 2) {
                ushort4v u;
                #pragma unroll
                for (int j = 0; j < 4; ++j) u[j] = f2bf(z[j]);
                *(ushort4v*)&outT[((size_t)b * N + n) * M + mb] = u;     // NHWC, 8B/lane
            }
            if (EPI == 1 || EPI == 3) {
                #pragma unroll
                for (int j = 0; j < 4; ++j)
                    outF[((size_t)b * M + mb + j) * N + n] = z[j];       // NCHW f32
            }
        }
    }
}

// ---------------------------------------------------------------------------
// Attention on NHWC bf16 qkv [B][6400][768] (chan = qsel*256 + di*64 + c).
// Flat grid 800, id&7 = batch -> XCD-local tap reuse. Wave di = dilation 1<<di.
// q kept bf16 in regs; branchless OOB; PV output -> bf16 LDS [di][px][c]
// with c-chunk XOR swizzle (px&7); two-pass fc-mix + LayerNorm (E[x^2] var).
// ---------------------------------------------------------------------------
__global__ __launch_bounds__(256, 4)
void attn_k(const short* __restrict__ qkvt,
            const float* __restrict__ fc_w, const float* __restrict__ fc_b,
            const float* __restrict__ ln_g, const float* __restrict__ ln_b,
            short* __restrict__ y2t)
{
    __shared__ short st[4][64][64];   // 32 KB, [di][px][c] chunk-swizzled

    const int id  = blockIdx.x;
    const int b   = id & 7;
    const int hw0 = (id >> 3) * 64;
    const int t   = threadIdx.x;
    const int di  = t >> 6;
    const int px  = t & 63;
    const int hw  = hw0 + px;
    const int yy  = hw / 80;
    const int xx  = hw % 80;
    const int r   = 1 << di;

    int   off[9];
    float okf[9];
    #pragma unroll
    for (int jy = 0; jy < 3; ++jy)
        #pragma unroll
        for (int jx = 0; jx < 3; ++jx) {
            const int ny = yy + (jy - 1) * r;
            const int nx = xx + (jx - 1) * r;
            const bool o = (ny >= 0) && (ny < 80) && (nx >= 0) && (nx < 80);
            okf[jy * 3 + jx] = o ? 1.f : 0.f;
            off[jy * 3 + jx] = o ? (ny * 80 + nx) : hw;
        }

    const short* qp = qkvt + ((size_t)(b * 6400 + hw)) * 768 + di * 64;

    // ---- scores (branchless: OOB rows load real data, zeroed after) ----
    float s[9];
    #pragma unroll
    for (int j = 0; j < 9; ++j) s[j] = 0.f;
    #pragma unroll
    for (int c8 = 0; c8 < 8; ++c8) {
        const short8 qv = *(const short8*)&qp[c8 * 8];
        float qf[8];
        #pragma unroll
        for (int u = 0; u < 8; ++u) qf[u] = bf2f((unsigned short)qv[u]);
        #pragma unroll
        for (int j = 0; j < 9; ++j) {
            const short8 kv = *(const short8*)(qkvt +
                ((size_t)(b * 6400 + off[j])) * 768 + 256 + di * 64 + c8 * 8);
            #pragma unroll
            for (int u = 0; u < 8; ++u)
                s[j] = fmaf(qf[u], bf2f((unsigned short)kv[u]), s[j]);
        }
    }
    #pragma unroll
    for (int j = 0; j < 9; ++j) s[j] *= okf[j] * 0.125f;   // scale + OOB logit=0

    // ---- softmax over 9 taps ----
    float mx = s[0];
    #pragma unroll
    for (int j = 1; j < 9; ++j) mx = fmaxf(mx, s[j]);
    float e[9], sum = 0.f;
    #pragma unroll
    for (int j = 0; j < 9; ++j) { e[j] = __expf(s[j] - mx); sum += e[j]; }
    const float isum = 1.f / sum;
    float pe[9];
    #pragma unroll
    for (int j = 0; j < 9; ++j) pe[j] = e[j] * isum * okf[j];  // OOB v contributes 0

    // ---- PV -> bf16 LDS (chunk-swizzled) ----
    #pragma unroll
    for (int c8 = 0; c8 < 8; ++c8) {
        float o[8];
        #pragma unroll
        for (int u = 0; u < 8; ++u) o[u] = 0.f;
        #pragma unroll
        for (int j = 0; j < 9; ++j) {
            const short8 vv = *(const short8*)(qkvt +
                ((size_t)(b * 6400 + off[j])) * 768 + 512 + di * 64 + c8 * 8);
            #pragma unroll
            for (int u = 0; u < 8; ++u)
                o[u] = fmaf(pe[j], bf2f((unsigned short)vv[u]), o[u]);
        }
        short8 ov;
        #pragma unroll
        for (int u = 0; u < 8; ++u) ov[u] = (short)f2bf(o[u]);
        *(short8*)&st[di][px][(c8 ^ (px & 7)) << 3] = ov;
    }
    __syncthreads();

    // ---- fc-mix + residual + LN(64), two-pass (no f[64] register array) ----
    float cw[4];
    #pragma unroll
    for (int s4 = 0; s4 < 4; ++s4) cw[s4] = fc_w[di * 4 + s4] + (s4 == di ? 1.f : 0.f);
    const float fb = fc_b[di];

    float mu = 0.f, sq = 0.f;
    #pragma unroll
    for (int c8 = 0; c8 < 8; ++c8) {
        const int cc = (c8 ^ (px & 7)) << 3;
        const short8 a0 = *(const short8*)&st[0][px][cc];
        const short8 a1 = *(const short8*)&st[1][px][cc];
        const short8 a2 = *(const short8*)&st[2][px][cc];
        const short8 a3 = *(const short8*)&st[3][px][cc];
        #pragma unroll
        for (int u = 0; u < 8; ++u) {
            float f = fb;
            f = fmaf(cw[0], bf2f((unsigned short)a0[u]), f);
            f = fmaf(cw[1], bf2f((unsigned short)a1[u]), f);
            f = fmaf(cw[2], bf2f((unsigned short)a2[u]), f);
            f = fmaf(cw[3], bf2f((unsigned short)a3[u]), f);
            mu += f; sq = fmaf(f, f, sq);
        }
    }
    mu *= (1.f / 64.f);
    const float var  = sq * (1.f / 64.f) - mu * mu;
    const float rstd = rsqrtf(var + EPS_F);

    short* yo = y2t + ((size_t)(b * 6400 + hw)) * 256 + di * 64;
    #pragma unroll
    for (int c8 = 0; c8 < 8; ++c8) {
        const int cc = (c8 ^ (px & 7)) << 3;
        const short8 a0 = *(const short8*)&st[0][px][cc];
        const short8 a1 = *(const short8*)&st[1][px][cc];
        const short8 a2 = *(const short8*)&st[2][px][cc];
        const short8 a3 = *(const short8*)&st[3][px][cc];
        short8 ov;
        #pragma unroll
        for (int u = 0; u < 8; ++u) {
            float f = fb;
            f = fmaf(cw[0], bf2f((unsigned short)a0[u]), f);
            f = fmaf(cw[1], bf2f((unsigned short)a1[u]), f);
            f = fmaf(cw[2], bf2f((unsigned short)a2[u]), f);
            f = fmaf(cw[3], bf2f((unsigned short)a3[u]), f);
            const int c = c8 * 8 + u;
            ov[u] = (short)f2bf((f - mu) * rstd * ln_g[c] + ln_b[c]);
        }
        *(short8*)&yo[c8 * 8] = ov;
    }
}

// ---------------------------------------------------------------------------
// x NCHW f32 -> xt NHWC bf16
// ---------------------------------------------------------------------------
__global__ void xt_k(const float* __restrict__ x, short* __restrict__ xt)
{
    const int b  = blockIdx.y;
    const int hw = blockIdx.x * 256 + threadIdx.x;
    const float* xb = x + (size_t)b * 256 * 6400 + hw;
    short* o = xt + ((size_t)b * 6400 + hw) * 256;
    #pragma unroll 4
    for (int c8 = 0; c8 < 32; ++c8) {
        short8 v;
        #pragma unroll
        for (int u = 0; u < 8; ++u)
            v[u] = (short)f2bf(xb[(size_t)(c8 * 8 + u) * 6400]);
        *(short8*)&o[c8 * 8] = v;
    }
}

// ---------------------------------------------------------------------------
// fp32 -> bf16 weight conversion (qkv_w | proj_w | w1 | w2 concatenated)
// ---------------------------------------------------------------------------
__global__ void wc_k(const float* __restrict__ a, const float* __restrict__ bb,
                     const float* __restrict__ c, const float* __restrict__ d,
                     short* __restrict__ o)
{
    const int i = blockIdx.x * 256 + threadIdx.x;   // 0 .. 524287
    float v;
    if      (i < 196608)  v = a[i];
    else if (i < 262144)  v = bb[i - 196608];
    else if (i < 393216)  v = c[i - 262144];
    else                  v = d[i - 393216];
    o[i] = (short)f2bf(v);
}

// ---------------------------------------------------------------------------
extern "C" void kernel_launch(void* const* d_in, const int* in_sizes, int n_in,
                              void* d_out, int out_size, void* d_ws, size_t ws_size,
                              hipStream_t stream)
{
    const float* x      = (const float*)d_in[0];
    const float* qkv_w  = (const float*)d_in[1];
    const float* qkv_b  = (const float*)d_in[2];
    const float* fc_w   = (const float*)d_in[3];
    const float* fc_b   = (const float*)d_in[4];
    const float* ln_g   = (const float*)d_in[5];
    const float* ln_b   = (const float*)d_in[6];
    const float* proj_w = (const float*)d_in[7];
    const float* proj_b = (const float*)d_in[8];
    const float* w1     = (const float*)d_in[9];
    const float* bn1_g  = (const float*)d_in[10];
    const float* bn1_b  = (const float*)d_in[11];
    const float* bn1_m  = (const float*)d_in[12];
    const float* bn1_v  = (const float*)d_in[13];
    const float* w2     = (const float*)d_in[14];
    const float* bn2_g  = (const float*)d_in[15];
    const float* bn2_b  = (const float*)d_in[16];
    const float* bn2_m  = (const float*)d_in[17];
    const float* bn2_v  = (const float*)d_in[18];
    float* out = (float*)d_out;

    const int B = 8;

    // workspace layout (bytes)
    char* ws = (char*)d_ws;
    short* wqkvb  = (short*)(ws + 0);                   // 196608 bf16
    short* wprojb = wqkvb + 196608;                     //  65536
    short* w1b    = wprojb + 65536;                     // 131072
    short* w2b    = w1b + 131072;                       // 131072
    short* xt     = (short*)(ws + 1048576);             // [B][HW][256]
    short* qkvt   = (short*)(ws + 27262976);            // [B][HW][768]; later h [B][HW][512]
    short* y2t    = (short*)(ws + 105906176);           // [B][HW][256]
    short* x1t    = (short*)(ws + 132120576);           // [B][HW][256]
    float* x1f    = (float*)(ws + 158334976);           // [B][256][HW] f32
    short* h      = qkvt;

    dim3 blk(256);

    // 0) weights -> bf16
    wc_k<<<dim3(2048), blk, 0, stream>>>(qkv_w, proj_w, w1, w2, wqkvb);

    // 1) x -> NHWC bf16
    xt_k<<<dim3(25, B), blk, 0, stream>>>(x, xt);

    // 2) qkv GEMM: M=768 K=256 -> qkvt NHWC (+bias)
    mm_k<0><<<dim3(50 * 6 * 8), blk, 0, stream>>>(
        wqkvb, xt, 768, 256, qkv_b, nullptr, nullptr, nullptr, nullptr,
        qkvt, nullptr);

    // 3) attention + fc-mix + LN -> y2t NHWC
    attn_k<<<dim3(800), blk, 0, stream>>>(qkvt, fc_w, fc_b, ln_g, ln_b, y2t);

    // 4) proj GEMM: M=256 K=256, +bias +x -> x1t (bf16 NHWC) and x1f (f32 NCHW)
    mm_k<1><<<dim3(50 * 2 * 8), blk, 0, stream>>>(
        wprojb, y2t, 256, 256, proj_b, nullptr, nullptr, nullptr, x,
        x1t, x1f);

    // 5) mlp1: M=512 K=256, BN1+SiLU -> h NHWC bf16
    mm_k<2><<<dim3(50 * 4 * 8), blk, 0, stream>>>(
        w1b, x1t, 512, 256, bn1_g, bn1_b, bn1_m, bn1_v, nullptr,
        h, nullptr);

    // 6) mlp2: M=256 K=512, BN2 + x1 resid -> out f32 NCHW
    mm_k<3><<<dim3(50 * 2 * 8), blk, 0, stream>>>(
        w2b, h, 256, 512, bn2_g, bn2_b, bn2_m, bn2_v, x1f,
        nullptr, out);
}

// Round 7
// 381.670 us; speedup vs baseline: 2.5115x; 1.1523x over previous
//
#include <hip/hip_runtime.h>

#define EPS_F 1e-5f

typedef __attribute__((ext_vector_type(8))) short short8;
typedef __attribute__((ext_vector_type(4))) float f32x4;
typedef __attribute__((ext_vector_type(4))) unsigned short ushort4v;
typedef __attribute__((address_space(1))) void gvoid;
typedef __attribute__((address_space(3))) void svoid;

__device__ __forceinline__ float bf2f(unsigned short u){
    union { unsigned int i; float f; } v; v.i = ((unsigned int)u) << 16; return v.f;
}
__device__ __forceinline__ unsigned short f2bf(float f){
    union { float f; unsigned int i; } v; v.f = f;
    unsigned int r = v.i + 0x7FFFu + ((v.i >> 16) & 1u);
    return (unsigned short)(r >> 16);
}

// ---------------------------------------------------------------------------
// bf16 MFMA GEMM (unchanged from R5): C[m][n] = sum_k A[m][k] * Act[n][k]
// Flat grid, XCD swizzle: id&7 = batch, id>>3 = n-tile + 50*m-tile.
// EPI 0: +bias              -> outT NHWC bf16            (qkv)
// EPI 1: +bias +resid(NCHW) -> outT NHWC bf16 + outF f32 (proj -> x1)
// EPI 2: BN+SiLU            -> outT NHWC bf16            (mlp1)
// EPI 3: BN+resid(NCHW)     -> outF f32 NCHW             (mlp2 -> out)
// ---------------------------------------------------------------------------
template<int EPI>
__global__ __launch_bounds__(256, 2)
void mm_k(const short* __restrict__ A, const short* __restrict__ Bt,
          const int M, const int K,
          const float* __restrict__ p0, const float* __restrict__ p1,
          const float* __restrict__ p2, const float* __restrict__ p3,
          const float* __restrict__ resid,
          short* __restrict__ outT, float* __restrict__ outF)
{
    const int N = 6400;
    __shared__ short lsA[128 * 64];
    __shared__ short lsB[128 * 64];

    const int id = blockIdx.x;
    const int b  = id & 7;
    const int rr = id >> 3;
    const int n0 = (rr % 50) * 128;
    const int m0 = (rr / 50) * 128;
    const int t  = threadIdx.x;
    const int l  = t & 63;
    const int w  = t >> 6;
    const int wr = w >> 1, wc = w & 1;

    const short* Bb = Bt + (size_t)b * N * K;

    f32x4 acc[4][4];
    #pragma unroll
    for (int i = 0; i < 4; ++i)
        #pragma unroll
        for (int j = 0; j < 4; ++j) acc[i][j] = (f32x4){0.f, 0.f, 0.f, 0.f};

    const int rsub = l >> 3;
    const int csub = l & 7;

    for (int k0 = 0; k0 < K; k0 += 64) {
        #pragma unroll
        for (int q = 0; q < 4; ++q) {
            const int row = (w * 4 + q) * 8 + rsub;
            const int cs  = csub ^ (row & 7);
            const short* ga = A  + (size_t)(m0 + row) * K + k0 + (cs << 3);
            __builtin_amdgcn_global_load_lds((gvoid*)ga, (svoid*)(lsA + (w * 4 + q) * 512), 16, 0, 0);
            const short* gb = Bb + (size_t)(n0 + row) * K + k0 + (cs << 3);
            __builtin_amdgcn_global_load_lds((gvoid*)gb, (svoid*)(lsB + (w * 4 + q) * 512), 16, 0, 0);
        }
        __syncthreads();

        #pragma unroll
        for (int ks = 0; ks < 2; ++ks) {
            short8 av[4], bv[4];
            const int cfr = ks * 4 + (l >> 4);
            #pragma unroll
            for (int mi = 0; mi < 4; ++mi) {
                const int row = wr * 64 + mi * 16 + (l & 15);
                av[mi] = *(const short8*)&lsA[row * 64 + ((cfr ^ (row & 7)) << 3)];
            }
            #pragma unroll
            for (int ni = 0; ni < 4; ++ni) {
                const int row = wc * 64 + ni * 16 + (l & 15);
                bv[ni] = *(const short8*)&lsB[row * 64 + ((cfr ^ (row & 7)) << 3)];
            }
            #pragma unroll
            for (int mi = 0; mi < 4; ++mi)
                #pragma unroll
                for (int ni = 0; ni < 4; ++ni)
                    acc[mi][ni] = __builtin_amdgcn_mfma_f32_16x16x32_bf16(
                        av[mi], bv[ni], acc[mi][ni], 0, 0, 0);
        }
        __syncthreads();
    }

    const int mq = (l >> 4) * 4;
    const int nq = l & 15;
    #pragma unroll
    for (int mi = 0; mi < 4; ++mi) {
        const int mb = m0 + wr * 64 + mi * 16 + mq;
        float mul[4], add[4];
        #pragma unroll
        for (int j = 0; j < 4; ++j) {
            const int m = mb + j;
            if (EPI == 0 || EPI == 1) { mul[j] = 1.f; add[j] = p0[m]; }
            else { const float inv = p0[m] * rsqrtf(p3[m] + EPS_F);
                   mul[j] = inv; add[j] = p1[m] - p2[m] * inv; }
        }
        #pragma unroll
        for (int ni = 0; ni < 4; ++ni) {
            const int n = n0 + wc * 64 + ni * 16 + nq;
            float z[4];
            #pragma unroll
            for (int j = 0; j < 4; ++j) {
                z[j] = acc[mi][ni][j] * mul[j] + add[j];
                if (EPI == 2) z[j] = z[j] / (1.f + __expf(-z[j]));
                if (EPI == 1 || EPI == 3)
                    z[j] += resid[((size_t)b * M + mb + j) * N + n];
            }
            if (EPI == 0 || EPI == 1 || EPI == 2) {
                ushort4v u;
                #pragma unroll
                for (int j = 0; j < 4; ++j) u[j] = f2bf(z[j]);
                *(ushort4v*)&outT[((size_t)b * N + n) * M + mb] = u;
            }
            if (EPI == 1 || EPI == 3) {
                #pragma unroll
                for (int j = 0; j < 4; ++j)
                    outF[((size_t)b * M + mb + j) * N + n] = z[j];
            }
        }
    }
}

// ---------------------------------------------------------------------------
// Attention, 4-way channel-split: thread = (px 0..15, cg 0..3, di 0..3).
// wave = di; lane = px + 16*cg. Each thread: 16 channels of one (px, di).
//   scores : per-lane partial dot over 16 ch, shfl_xor(16/32) reduce over cg
//   softmax: redundant per lane (9 taps)
//   PV     : 16 output channels per lane -> swizzled 8 KB LDS [di][px][c]
//   fc-mix + LN(64): read 4 dilations from LDS, mean/var via shfl over cg
// Grid 3200 (= 8 batch * 400 strips), id&7 = batch -> XCD-local L2 reuse.
// ---------------------------------------------------------------------------
__global__ __launch_bounds__(256, 4)
void attn_k(const short* __restrict__ qkvt,
            const float* __restrict__ fc_w, const float* __restrict__ fc_b,
            const float* __restrict__ ln_g, const float* __restrict__ ln_b,
            short* __restrict__ y2t)
{
    __shared__ short st[4][16][64];   // 8 KB, chunk-swizzled in c

    const int id  = blockIdx.x;
    const int b   = id & 7;
    const int hw0 = (id >> 3) * 16;
    const int t   = threadIdx.x;
    const int px  = t & 15;
    const int cg  = (t >> 4) & 3;
    const int di  = t >> 6;
    const int hw  = hw0 + px;
    const int yy  = hw / 80;
    const int xx  = hw % 80;
    const int r   = 1 << di;

    int   off[9];
    float okf[9];
    #pragma unroll
    for (int jy = 0; jy < 3; ++jy)
        #pragma unroll
        for (int jx = 0; jx < 3; ++jx) {
            const int ny = yy + (jy - 1) * r;
            const int nx = xx + (jx - 1) * r;
            const bool o = (ny >= 0) && (ny < 80) && (nx >= 0) && (nx < 80);
            okf[jy * 3 + jx] = o ? 1.f : 0.f;
            off[jy * 3 + jx] = o ? (ny * 80 + nx) : hw;
        }

    const short* base = qkvt + (size_t)b * 6400 * 768;
    const int ch = di * 64 + cg * 16;          // my 16-channel base

    // ---- q (16 ch) ----
    const short8 qv0 = *(const short8*)(base + (size_t)hw * 768 + ch);
    const short8 qv1 = *(const short8*)(base + (size_t)hw * 768 + ch + 8);
    float qf[16];
    #pragma unroll
    for (int u = 0; u < 8; ++u) { qf[u] = bf2f((unsigned short)qv0[u]);
                                  qf[8 + u] = bf2f((unsigned short)qv1[u]); }

    // ---- partial scores over my 16 channels (9 independent tap streams) ----
    float s[9];
    #pragma unroll
    for (int j = 0; j < 9; ++j) {
        const short* kp = base + (size_t)off[j] * 768 + 256 + ch;
        const short8 k0 = *(const short8*)kp;
        const short8 k1 = *(const short8*)(kp + 8);
        float a = 0.f;
        #pragma unroll
        for (int u = 0; u < 8; ++u) {
            a = fmaf(qf[u],     bf2f((unsigned short)k0[u]), a);
            a = fmaf(qf[8 + u], bf2f((unsigned short)k1[u]), a);
        }
        s[j] = a;
    }

    // ---- reduce over the 4 channel-group lanes (stride 16, 32) ----
    #pragma unroll
    for (int j = 0; j < 9; ++j) {
        s[j] += __shfl_xor(s[j], 16, 64);
        s[j] += __shfl_xor(s[j], 32, 64);
        s[j] *= okf[j] * 0.125f;               // scale; OOB logit = 0
    }

    // ---- softmax over 9 taps (redundant per lane) ----
    float mx = s[0];
    #pragma unroll
    for (int j = 1; j < 9; ++j) mx = fmaxf(mx, s[j]);
    float e[9], sum = 0.f;
    #pragma unroll
    for (int j = 0; j < 9; ++j) { e[j] = __expf(s[j] - mx); sum += e[j]; }
    const float isum = 1.f / sum;
    float pe[9];
    #pragma unroll
    for (int j = 0; j < 9; ++j) pe[j] = e[j] * isum * okf[j];  // OOB v -> 0

    // ---- PV: 16 output channels ----
    float o[16];
    #pragma unroll
    for (int u = 0; u < 16; ++u) o[u] = 0.f;
    #pragma unroll
    for (int j = 0; j < 9; ++j) {
        const short* vp = base + (size_t)off[j] * 768 + 512 + ch;
        const short8 v0 = *(const short8*)vp;
        const short8 v1 = *(const short8*)(vp + 8);
        #pragma unroll
        for (int u = 0; u < 8; ++u) {
            o[u]     = fmaf(pe[j], bf2f((unsigned short)v0[u]), o[u]);
            o[8 + u] = fmaf(pe[j], bf2f((unsigned short)v1[u]), o[8 + u]);
        }
    }
    short8 ov0, ov1;
    #pragma unroll
    for (int u = 0; u < 8; ++u) { ov0[u] = (short)f2bf(o[u]);
                                  ov1[u] = (short)f2bf(o[8 + u]); }
    // swizzled LDS write: chunk (cg*2+h) ^ (px&7)
    short* sp = &st[di][px][0];
    *(short8*)(sp + (((cg * 2)     ^ (px & 7)) << 3)) = ov0;
    *(short8*)(sp + (((cg * 2 + 1) ^ (px & 7)) << 3)) = ov1;
    __syncthreads();

    // ---- fc-mix (+own-dilation residual) + LayerNorm(64) ----
    float cw[4];
    #pragma unroll
    for (int s4 = 0; s4 < 4; ++s4) cw[s4] = fc_w[di * 4 + s4] + (s4 == di ? 1.f : 0.f);
    const float fb = fc_b[di];

    const int cc0 = ((cg * 2)     ^ (px & 7)) << 3;
    const int cc1 = ((cg * 2 + 1) ^ (px & 7)) << 3;
    float f[16];
    #pragma unroll
    for (int u = 0; u < 16; ++u) f[u] = fb;
    #pragma unroll
    for (int s4 = 0; s4 < 4; ++s4) {
        const short8 a0 = *(const short8*)(&st[s4][px][0] + cc0);
        const short8 a1 = *(const short8*)(&st[s4][px][0] + cc1);
        #pragma unroll
        for (int u = 0; u < 8; ++u) {
            f[u]     = fmaf(cw[s4], bf2f((unsigned short)a0[u]), f[u]);
            f[8 + u] = fmaf(cw[s4], bf2f((unsigned short)a1[u]), f[8 + u]);
        }
    }
    float mu = 0.f, sq = 0.f;
    #pragma unroll
    for (int u = 0; u < 16; ++u) { mu += f[u]; sq = fmaf(f[u], f[u], sq); }
    mu += __shfl_xor(mu, 16, 64);  mu += __shfl_xor(mu, 32, 64);
    sq += __shfl_xor(sq, 16, 64);  sq += __shfl_xor(sq, 32, 64);
    mu *= (1.f / 64.f);
    const float var  = sq * (1.f / 64.f) - mu * mu;
    const float rstd = rsqrtf(var + EPS_F);

    short* yo = y2t + ((size_t)(b * 6400 + hw)) * 256 + ch;
    short8 y0, y1;
    #pragma unroll
    for (int u = 0; u < 8; ++u) {
        const int c0 = cg * 16 + u, c1 = cg * 16 + 8 + u;
        y0[u] = (short)f2bf((f[u]     - mu) * rstd * ln_g[c0] + ln_b[c0]);
        y1[u] = (short)f2bf((f[8 + u] - mu) * rstd * ln_g[c1] + ln_b[c1]);
    }
    *(short8*)yo       = y0;
    *(short8*)(yo + 8) = y1;
}

// ---------------------------------------------------------------------------
// x NCHW f32 -> xt NHWC bf16
// ---------------------------------------------------------------------------
__global__ void xt_k(const float* __restrict__ x, short* __restrict__ xt)
{
    const int b  = blockIdx.y;
    const int hw = blockIdx.x * 256 + threadIdx.x;
    const float* xb = x + (size_t)b * 256 * 6400 + hw;
    short* o = xt + ((size_t)b * 6400 + hw) * 256;
    #pragma unroll 4
    for (int c8 = 0; c8 < 32; ++c8) {
        short8 v;
        #pragma unroll
        for (int u = 0; u < 8; ++u)
            v[u] = (short)f2bf(xb[(size_t)(c8 * 8 + u) * 6400]);
        *(short8*)&o[c8 * 8] = v;
    }
}

// ---------------------------------------------------------------------------
// fp32 -> bf16 weight conversion (qkv_w | proj_w | w1 | w2 concatenated)
// ---------------------------------------------------------------------------
__global__ void wc_k(const float* __restrict__ a, const float* __restrict__ bb,
                     const float* __restrict__ c, const float* __restrict__ d,
                     short* __restrict__ o)
{
    const int i = blockIdx.x * 256 + threadIdx.x;
    float v;
    if      (i < 196608)  v = a[i];
    else if (i < 262144)  v = bb[i - 196608];
    else if (i < 393216)  v = c[i - 262144];
    else                  v = d[i - 393216];
    o[i] = (short)f2bf(v);
}

// ---------------------------------------------------------------------------
extern "C" void kernel_launch(void* const* d_in, const int* in_sizes, int n_in,
                              void* d_out, int out_size, void* d_ws, size_t ws_size,
                              hipStream_t stream)
{
    const float* x      = (const float*)d_in[0];
    const float* qkv_w  = (const float*)d_in[1];
    const float* qkv_b  = (const float*)d_in[2];
    const float* fc_w   = (const float*)d_in[3];
    const float* fc_b   = (const float*)d_in[4];
    const float* ln_g   = (const float*)d_in[5];
    const float* ln_b   = (const float*)d_in[6];
    const float* proj_w = (const float*)d_in[7];
    const float* proj_b = (const float*)d_in[8];
    const float* w1     = (const float*)d_in[9];
    const float* bn1_g  = (const float*)d_in[10];
    const float* bn1_b  = (const float*)d_in[11];
    const float* bn1_m  = (const float*)d_in[12];
    const float* bn1_v  = (const float*)d_in[13];
    const float* w2     = (const float*)d_in[14];
    const float* bn2_g  = (const float*)d_in[15];
    const float* bn2_b  = (const float*)d_in[16];
    const float* bn2_m  = (const float*)d_in[17];
    const float* bn2_v  = (const float*)d_in[18];
    float* out = (float*)d_out;

    const int B = 8;

    char* ws = (char*)d_ws;
    short* wqkvb  = (short*)(ws + 0);                   // 196608 bf16
    short* wprojb = wqkvb + 196608;                     //  65536
    short* w1b    = wprojb + 65536;                     // 131072
    short* w2b    = w1b + 131072;                       // 131072
    short* xt     = (short*)(ws + 1048576);             // [B][HW][256]
    short* qkvt   = (short*)(ws + 27262976);            // [B][HW][768]; later h
    short* y2t    = (short*)(ws + 105906176);           // [B][HW][256]
    short* x1t    = (short*)(ws + 132120576);           // [B][HW][256]
    float* x1f    = (float*)(ws + 158334976);           // [B][256][HW] f32
    short* h      = qkvt;

    dim3 blk(256);

    // 0) weights -> bf16
    wc_k<<<dim3(2048), blk, 0, stream>>>(qkv_w, proj_w, w1, w2, wqkvb);

    // 1) x -> NHWC bf16
    xt_k<<<dim3(25, B), blk, 0, stream>>>(x, xt);

    // 2) qkv GEMM: M=768 K=256 -> qkvt NHWC (+bias)
    mm_k<0><<<dim3(50 * 6 * 8), blk, 0, stream>>>(
        wqkvb, xt, 768, 256, qkv_b, nullptr, nullptr, nullptr, nullptr,
        qkvt, nullptr);

    // 3) attention + fc-mix + LN -> y2t NHWC  (16 px per block, 3200 blocks)
    attn_k<<<dim3(3200), blk, 0, stream>>>(qkvt, fc_w, fc_b, ln_g, ln_b, y2t);

    // 4) proj GEMM: M=256 K=256, +bias +x -> x1t (bf16 NHWC) and x1f (f32 NCHW)
    mm_k<1><<<dim3(50 * 2 * 8), blk, 0, stream>>>(
        wprojb, y2t, 256, 256, proj_b, nullptr, nullptr, nullptr, x,
        x1t, x1f);

    // 5) mlp1: M=512 K=256, BN1+SiLU -> h NHWC bf16
    mm_k<2><<<dim3(50 * 4 * 8), blk, 0, stream>>>(
        w1b, x1t, 512, 256, bn1_g, bn1_b, bn1_m, bn1_v, nullptr,
        h, nullptr);

    // 6) mlp2: M=256 K=512, BN2 + x1 resid -> out f32 NCHW
    mm_k<3><<<dim3(50 * 2 * 8), blk, 0, stream>>>(
        w2b, h, 256, 512, bn2_g, bn2_b, bn2_m, bn2_v, x1f,
        nullptr, out);
}